// Round 8
// baseline (104.207 us; speedup 1.0000x reference)
//
#include <hip/hip_runtime.h>
#include <hip/hip_bf16.h>
#include <math.h>

#define S_LEN 128
#define D_DIM 768
#define P_PAIRS 1024
#define B_BATCH 16

typedef __attribute__((ext_vector_type(8))) short bf16x8;
typedef __attribute__((ext_vector_type(4))) float f32x4;

#define PB_UNITS (B_BATCH * (D_DIM / 64))           // 192
#define T1_UNITS ((2304 / 64) * (1536 / 64))        // 36*24 = 864
#define T2_UNITS ((1536 / 64) * (768 / 64))         // 24*12 = 288
#define T3_UNITS ((768 / 64) * (128 / 64))          // 12*2  = 24

union SmemU {
    struct {
        ushort semb[128][64];    // emb chunk, bf16-rounded
        ushort spref[128][64];   // prefix max (bf16)
        ushort ssuf[128][64];    // suffix max (bf16)
        ushort smean[64];
        float  lred[3][4][64];
        int    li;
    } pb;                        // ~52.4 KB -> 3 blocks/CU
    float t64[64][65];           // transpose tile (16.6 KB)
};

__device__ __forceinline__ ushort f2bf(float f) {
    __hip_bfloat16 h = __float2bfloat16(f);
    return *(ushort*)&h;
}

__device__ __forceinline__ float bf2f(ushort u) {
    unsigned int x = ((unsigned int)u) << 16;
    float f;
    __builtin_memcpy(&f, &x, 4);
    return f;
}

// ---------------------------------------------------------------------------
// Fused prep kernel (unchanged from round 7).
//   blocks [0,192):     per-(batch, 64-col-chunk) span scan + X build
//   blocks [192,1368):  weight transposes, 64x64 tiles (f32 [K,N] -> bf16 [N,K])
// ---------------------------------------------------------------------------
__global__ __launch_bounds__(256) void fused_prep_kernel(
    const float* __restrict__ emb_all,   // [B,S,D]
    const int* __restrict__ span_masks,  // [B,S]
    const int* __restrict__ batch_idx,   // [P]
    const int* __restrict__ aspect_idx,  // [P]
    const int* __restrict__ opinion_idx, // [P]
    ushort* __restrict__ X,              // [P, 3*D] bf16
    const float* __restrict__ W1, ushort* __restrict__ W1t,
    const float* __restrict__ W2, ushort* __restrict__ W2t,
    const float* __restrict__ W3, ushort* __restrict__ W3t)
{
    __shared__ SmemU sm;
    int bid = blockIdx.x;
    int tid = threadIdx.x;

    if (bid < PB_UNITS) {
        // ================= span scan + X build =================
        int b = bid / (D_DIM / 64);
        int chunk = bid % (D_DIM / 64);
        int lane = tid & 63;
        int g = tid >> 6;           // wave/row-group 0..3
        int r0 = g * 32;
        int col = chunk * 64 + lane;

        if (tid == 0) {
            int s = 0;
            for (int i = 0; i < S_LEN; ++i) s += span_masks[b * S_LEN + i];
            sm.pb.li = s - 1;
        }
        __syncthreads();
        int li = sm.pb.li;

        const float* embb = emb_all + (size_t)b * S_LEN * D_DIM;

        float v[32];
        #pragma unroll
        for (int r = 0; r < 32; ++r) {
            v[r] = embb[(size_t)(r0 + r) * D_DIM + col];
            sm.pb.semb[r0 + r][lane] = f2bf(v[r]);
        }

        float wmax = -INFINITY, umax = -INFINITY, s = 0.f;
        #pragma unroll
        for (int r = 0; r < 32; ++r) {
            int gr = r0 + r;
            wmax = fmaxf(wmax, (gr == 0) ? -INFINITY : v[r]);
            bool in = (gr >= 1) && (gr < li);
            umax = fmaxf(umax, in ? v[r] : -INFINITY);
            s += in ? v[r] : 0.f;
        }
        sm.pb.lred[0][g][lane] = wmax;
        sm.pb.lred[1][g][lane] = umax;
        sm.pb.lred[2][g][lane] = s;
        __syncthreads();

        float basep = -INFINITY;
        #pragma unroll
        for (int gg = 0; gg < 3; ++gg)
            if (gg < g) basep = fmaxf(basep, sm.pb.lred[0][gg][lane]);
        float bases = -INFINITY;
        #pragma unroll
        for (int gg = 1; gg < 4; ++gg)
            if (gg > g) bases = fmaxf(bases, sm.pb.lred[1][gg][lane]);

        if (g == 0) {
            float tot = sm.pb.lred[2][0][lane] + sm.pb.lred[2][1][lane]
                      + sm.pb.lred[2][2][lane] + sm.pb.lred[2][3][lane];
            int cnt = (li - 1) > 0 ? (li - 1) : 1;
            sm.pb.smean[lane] = f2bf(tot / (float)cnt);
        }

        float m = basep;
        #pragma unroll
        for (int r = 0; r < 32; ++r) {
            int gr = r0 + r;
            m = fmaxf(m, (gr == 0) ? -INFINITY : v[r]);
            sm.pb.spref[gr][lane] = f2bf(m);
        }
        float m2 = bases;
        #pragma unroll
        for (int r = 31; r >= 0; --r) {
            int gr = r0 + r;
            bool in = (gr >= 1) && (gr < li);
            m2 = fmaxf(m2, in ? v[r] : -INFINITY);
            if (gr >= 1) sm.pb.ssuf[gr][lane] = f2bf(m2);
        }
        __syncthreads();

        // pair loop: wave g scans pairs [g*256, (g+1)*256), ballot over batch
        int pbase = g * 256;
        for (int c = 0; c < 256; c += 64) {
            int p = pbase + c + lane;
            int vb = batch_idx[p];
            int va = aspect_idx[p];
            int vo = opinion_idx[p];
            unsigned long long mask = __ballot(vb == b);
            while (mask) {
                int i = __ffsll((long long)mask) - 1;
                mask &= mask - 1;
                int pp = pbase + c + i;
                int a = __shfl(va, i);
                int o = __shfl(vo, i);
                bool both0 = (a == 0) && (o == 0);
                int bnd = (a != 0) ? a : o;
                int oe = (o == 0) ? li : o;
                float ar  = bf2f(sm.pb.semb[a][lane]);
                float orp = bf2f(sm.pb.semb[oe][lane]);
                ushort left, right;
                if (both0) {
                    left  = sm.pb.smean[lane];
                    right = sm.pb.spref[li - 1][lane];
                } else {
                    left  = (bnd == 1)  ? sm.pb.semb[0][lane]
                                        : sm.pb.spref[bnd - 1][lane];
                    right = (bnd == li) ? sm.pb.semb[li][lane]
                                        : sm.pb.ssuf[bnd][lane];
                }
                size_t base = (size_t)pp * (3 * D_DIM) + col;
                X[base]             = f2bf(ar + orp);
                X[base + D_DIM]     = left;
                X[base + 2 * D_DIM] = right;
            }
        }
    } else {
        // ================= weight transposes (64x64 tiles) =================
        int tb = bid - PB_UNITS;
        const float* in; ushort* out; int K, N, Npad, bx, by;
        if (tb < T1_UNITS) {
            in = W1; out = W1t; K = 2304; N = 1536; Npad = 1536;
            bx = tb % (2304 / 64); by = tb / (2304 / 64);
        } else if (tb < T1_UNITS + T2_UNITS) {
            tb -= T1_UNITS;
            in = W2; out = W2t; K = 1536; N = 768; Npad = 768;
            bx = tb % (1536 / 64); by = tb / (1536 / 64);
        } else {
            tb -= T1_UNITS + T2_UNITS;
            in = W3; out = W3t; K = 768; N = 121; Npad = 128;
            bx = tb % (768 / 64); by = tb / (768 / 64);
        }
        int k0 = bx * 64, n0 = by * 64;

        int kr = tid >> 2;
        int nq = (tid & 3) * 16;
        if (n0 + 64 <= N) {
            #pragma unroll
            for (int j = 0; j < 4; ++j) {
                float4 vv = *(const float4*)&in[(size_t)(k0 + kr) * N + n0 + nq + j * 4];
                *(float4*)&sm.t64[kr][nq + j * 4] = vv;
            }
        } else {
            #pragma unroll
            for (int j = 0; j < 16; ++j) {
                int n = n0 + nq + j;
                sm.t64[kr][nq + j] = (n < N) ? in[(size_t)(k0 + kr) * N + n] : 0.f;
            }
        }
        __syncthreads();

        int nr = tid >> 2;
        int kq = (tid & 3) * 16;
        if (n0 + nr < Npad) {
            ushort tmp[16];
            #pragma unroll
            for (int j = 0; j < 16; ++j) tmp[j] = f2bf(sm.t64[kq + j][nr]);
            ushort* dst = out + (size_t)(n0 + nr) * K + k0 + kq;
            *(bf16x8*)dst       = *(bf16x8*)&tmp[0];
            *(bf16x8*)(dst + 8) = *(bf16x8*)&tmp[8];
        }
    }
}

// ---------------------------------------------------------------------------
// LDS-free direct-fragment MFMA GEMM.
// One wave (64 threads) per block; wave owns a 64x64 output tile (4x4 frags
// of 16x16x32). Fragments loaded straight from global ([row][K] bf16, all
// L2-resident): lane l <- [row0 + f*16 + (l&15)][k + (l>>4)*8 .. +8] = one
// 16B load. 3-deep rotating register pipeline; K/32 divisible by 3 for all
// layers (72/48/24). No LDS, no barriers.
// ---------------------------------------------------------------------------
template<int WRITE_BF16, int RELU>
__global__ __launch_bounds__(64) void gemm_direct(
    const ushort* __restrict__ A,    // [M,K] bf16
    const ushort* __restrict__ Bt,   // [Npad,K] bf16
    const float* __restrict__ bias,  // [N]
    void* __restrict__ Cout,         // [M,N]
    int M, int N, int K)
{
    int lane = threadIdx.x;
    int row0 = blockIdx.y * 64;
    int col0 = blockIdx.x * 64;
    int rl = lane & 15;
    int kl = (lane >> 4) * 8;

    const ushort* Ab = A  + (size_t)row0 * K + kl;
    const ushort* Bb = Bt + (size_t)col0 * K + kl;

    f32x4 acc[4][4] = {};
    bf16x8 a0[4], b0[4], a1[4], b1[4], a2[4], b2[4];

    #define LOADF(AS, BS, KO)                                                  \
        do {                                                                   \
            _Pragma("unroll")                                                  \
            for (int f = 0; f < 4; ++f) {                                      \
                AS[f] = *(const bf16x8*)(Ab + (size_t)(f * 16 + rl) * K + (KO)); \
                BS[f] = *(const bf16x8*)(Bb + (size_t)(f * 16 + rl) * K + (KO)); \
            }                                                                  \
        } while (0)

    #define MFMAS(AS, BS)                                                      \
        do {                                                                   \
            _Pragma("unroll")                                                  \
            for (int m = 0; m < 4; ++m)                                        \
                _Pragma("unroll")                                              \
                for (int n = 0; n < 4; ++n)                                    \
                    acc[m][n] = __builtin_amdgcn_mfma_f32_16x16x32_bf16(       \
                        AS[m], BS[n], acc[m][n], 0, 0, 0);                     \
        } while (0)

    int nk = K >> 5;                 // steps of k=32 (divisible by 3)
    LOADF(a0, b0, 0);
    LOADF(a1, b1, 32);
    for (int t = 0; t < nk; t += 3) {
        if (t + 2 < nk) LOADF(a2, b2, (size_t)(t + 2) * 32);
        MFMAS(a0, b0);
        if (t + 3 < nk) LOADF(a0, b0, (size_t)(t + 3) * 32);
        MFMAS(a1, b1);
        if (t + 4 < nk) LOADF(a1, b1, (size_t)(t + 4) * 32);
        MFMAS(a2, b2);
    }
    #undef LOADF
    #undef MFMAS

    // epilogue: C/D layout col = lane&15, row = (lane>>4)*4 + j
    #pragma unroll
    for (int m = 0; m < 4; ++m) {
        #pragma unroll
        for (int n = 0; n < 4; ++n) {
            #pragma unroll
            for (int j = 0; j < 4; ++j) {
                int row = row0 + m * 16 + (lane >> 4) * 4 + j;
                int col = col0 + n * 16 + rl;
                if (col < N && row < M) {
                    float v = acc[m][n][j] + bias[col];
                    if (RELU) v = fmaxf(v, 0.f);
                    if (WRITE_BF16)
                        ((ushort*)Cout)[(size_t)row * N + col] = f2bf(v);
                    else
                        ((float*)Cout)[(size_t)row * N + col] = v;
                }
            }
        }
    }
}

// ---------------------------------------------------------------------------
extern "C" void kernel_launch(void* const* d_in, const int* in_sizes, int n_in,
                              void* d_out, int out_size, void* d_ws, size_t ws_size,
                              hipStream_t stream) {
    const float* emb        = (const float*)d_in[0];
    const float* W1         = (const float*)d_in[1];  // [2304,1536]
    const float* b1         = (const float*)d_in[2];
    const float* W2         = (const float*)d_in[3];  // [1536,768]
    const float* b2         = (const float*)d_in[4];
    const float* W3         = (const float*)d_in[5];  // [768,121]
    const float* b3         = (const float*)d_in[6];
    const int* span_masks   = (const int*)d_in[7];
    const int* batch_idx    = (const int*)d_in[8];
    const int* aspect_idx   = (const int*)d_in[9];
    const int* opinion_idx  = (const int*)d_in[10];
    float* out = (float*)d_out;                       // [1024,121]

    // workspace (ushort units); H2 aliases Xb (Xb dead after GEMM1)
    ushort* Xb  = (ushort*)d_ws;                        // 2,359,296
    ushort* H2  = Xb;
    ushort* W1t = Xb  + (size_t)1024 * 2304;            // 3,538,944
    ushort* W2t = W1t + (size_t)1536 * 2304;            // 1,179,648
    ushort* W3t = W2t + (size_t)768 * 1536;             // 98,304
    ushort* H1  = W3t + (size_t)128 * 768;              // 1,572,864

    fused_prep_kernel<<<PB_UNITS + T1_UNITS + T2_UNITS + T3_UNITS, 256, 0, stream>>>(
        emb, span_masks, batch_idx, aspect_idx, opinion_idx, Xb,
        W1, W1t, W2, W2t, W3, W3t);

    gemm_direct<1,1><<<dim3(1536/64, 1024/64), 64, 0, stream>>>(Xb, W1t, b1, H1, 1024, 1536, 2304);
    gemm_direct<1,1><<<dim3( 768/64, 1024/64), 64, 0, stream>>>(H1, W2t, b2, H2, 1024, 768, 1536);
    gemm_direct<0,0><<<dim3( 128/64, 1024/64), 64, 0, stream>>>(H2, W3t, b3, out, 1024, 121, 768);
}

// Round 9
// 90.250 us; speedup vs baseline: 1.1547x; 1.1547x over previous
//
#include <hip/hip_runtime.h>
#include <hip/hip_bf16.h>
#include <math.h>

#define S_LEN 128
#define D_DIM 768
#define P_PAIRS 1024
#define B_BATCH 16

typedef __attribute__((ext_vector_type(8))) short bf16x8;
typedef __attribute__((ext_vector_type(4))) float f32x4;

#define PB_UNITS (B_BATCH * (D_DIM / 64))           // 192
#define T1_UNITS ((2304 / 64) * (1536 / 64))        // 36*24 = 864
#define T2_UNITS ((1536 / 64) * (768 / 64))         // 24*12 = 288
#define T3_UNITS ((768 / 64) * (128 / 64))          // 12*2  = 24

union SmemU {
    struct {
        ushort semb[128][64];    // emb chunk, bf16-rounded
        ushort spref[128][64];   // prefix max (bf16)
        ushort ssuf[128][64];    // suffix max (bf16)
        ushort smean[64];
        float  lred[3][4][64];
        int    li;
    } pb;                        // ~52.4 KB -> 3 blocks/CU
    float t64[64][65];           // transpose tile (16.6 KB)
};

__device__ __forceinline__ ushort f2bf(float f) {
    __hip_bfloat16 h = __float2bfloat16(f);
    return *(ushort*)&h;
}

__device__ __forceinline__ float bf2f(ushort u) {
    unsigned int x = ((unsigned int)u) << 16;
    float f;
    __builtin_memcpy(&f, &x, 4);
    return f;
}

__device__ __forceinline__ void gload16(const void* g, void* l) {
    __builtin_amdgcn_global_load_lds(
        (const __attribute__((address_space(1))) void*)g,
        (__attribute__((address_space(3))) void*)l, 16, 0, 0);
}

// ---------------------------------------------------------------------------
// Fused prep kernel (unchanged from round 7).
// ---------------------------------------------------------------------------
__global__ __launch_bounds__(256) void fused_prep_kernel(
    const float* __restrict__ emb_all,   // [B,S,D]
    const int* __restrict__ span_masks,  // [B,S]
    const int* __restrict__ batch_idx,   // [P]
    const int* __restrict__ aspect_idx,  // [P]
    const int* __restrict__ opinion_idx, // [P]
    ushort* __restrict__ X,              // [P, 3*D] bf16
    const float* __restrict__ W1, ushort* __restrict__ W1t,
    const float* __restrict__ W2, ushort* __restrict__ W2t,
    const float* __restrict__ W3, ushort* __restrict__ W3t)
{
    __shared__ SmemU sm;
    int bid = blockIdx.x;
    int tid = threadIdx.x;

    if (bid < PB_UNITS) {
        // ================= span scan + X build =================
        int b = bid / (D_DIM / 64);
        int chunk = bid % (D_DIM / 64);
        int lane = tid & 63;
        int g = tid >> 6;           // wave/row-group 0..3
        int r0 = g * 32;
        int col = chunk * 64 + lane;

        if (tid == 0) {
            int s = 0;
            for (int i = 0; i < S_LEN; ++i) s += span_masks[b * S_LEN + i];
            sm.pb.li = s - 1;
        }
        __syncthreads();
        int li = sm.pb.li;

        const float* embb = emb_all + (size_t)b * S_LEN * D_DIM;

        float v[32];
        #pragma unroll
        for (int r = 0; r < 32; ++r) {
            v[r] = embb[(size_t)(r0 + r) * D_DIM + col];
            sm.pb.semb[r0 + r][lane] = f2bf(v[r]);
        }

        float wmax = -INFINITY, umax = -INFINITY, s = 0.f;
        #pragma unroll
        for (int r = 0; r < 32; ++r) {
            int gr = r0 + r;
            wmax = fmaxf(wmax, (gr == 0) ? -INFINITY : v[r]);
            bool in = (gr >= 1) && (gr < li);
            umax = fmaxf(umax, in ? v[r] : -INFINITY);
            s += in ? v[r] : 0.f;
        }
        sm.pb.lred[0][g][lane] = wmax;
        sm.pb.lred[1][g][lane] = umax;
        sm.pb.lred[2][g][lane] = s;
        __syncthreads();

        float basep = -INFINITY;
        #pragma unroll
        for (int gg = 0; gg < 3; ++gg)
            if (gg < g) basep = fmaxf(basep, sm.pb.lred[0][gg][lane]);
        float bases = -INFINITY;
        #pragma unroll
        for (int gg = 1; gg < 4; ++gg)
            if (gg > g) bases = fmaxf(bases, sm.pb.lred[1][gg][lane]);

        if (g == 0) {
            float tot = sm.pb.lred[2][0][lane] + sm.pb.lred[2][1][lane]
                      + sm.pb.lred[2][2][lane] + sm.pb.lred[2][3][lane];
            int cnt = (li - 1) > 0 ? (li - 1) : 1;
            sm.pb.smean[lane] = f2bf(tot / (float)cnt);
        }

        float m = basep;
        #pragma unroll
        for (int r = 0; r < 32; ++r) {
            int gr = r0 + r;
            m = fmaxf(m, (gr == 0) ? -INFINITY : v[r]);
            sm.pb.spref[gr][lane] = f2bf(m);
        }
        float m2 = bases;
        #pragma unroll
        for (int r = 31; r >= 0; --r) {
            int gr = r0 + r;
            bool in = (gr >= 1) && (gr < li);
            m2 = fmaxf(m2, in ? v[r] : -INFINITY);
            if (gr >= 1) sm.pb.ssuf[gr][lane] = f2bf(m2);
        }
        __syncthreads();

        // pair loop: wave g scans pairs [g*256, (g+1)*256), ballot over batch
        int pbase = g * 256;
        for (int c = 0; c < 256; c += 64) {
            int p = pbase + c + lane;
            int vb = batch_idx[p];
            int va = aspect_idx[p];
            int vo = opinion_idx[p];
            unsigned long long mask = __ballot(vb == b);
            while (mask) {
                int i = __ffsll((long long)mask) - 1;
                mask &= mask - 1;
                int pp = pbase + c + i;
                int a = __shfl(va, i);
                int o = __shfl(vo, i);
                bool both0 = (a == 0) && (o == 0);
                int bnd = (a != 0) ? a : o;
                int oe = (o == 0) ? li : o;
                float ar  = bf2f(sm.pb.semb[a][lane]);
                float orp = bf2f(sm.pb.semb[oe][lane]);
                ushort left, right;
                if (both0) {
                    left  = sm.pb.smean[lane];
                    right = sm.pb.spref[li - 1][lane];
                } else {
                    left  = (bnd == 1)  ? sm.pb.semb[0][lane]
                                        : sm.pb.spref[bnd - 1][lane];
                    right = (bnd == li) ? sm.pb.semb[li][lane]
                                        : sm.pb.ssuf[bnd][lane];
                }
                size_t base = (size_t)pp * (3 * D_DIM) + col;
                X[base]             = f2bf(ar + orp);
                X[base + D_DIM]     = left;
                X[base + 2 * D_DIM] = right;
            }
        }
    } else {
        // ================= weight transposes (64x64 tiles) =================
        int tb = bid - PB_UNITS;
        const float* in; ushort* out; int K, N, Npad, bx, by;
        if (tb < T1_UNITS) {
            in = W1; out = W1t; K = 2304; N = 1536; Npad = 1536;
            bx = tb % (2304 / 64); by = tb / (2304 / 64);
        } else if (tb < T1_UNITS + T2_UNITS) {
            tb -= T1_UNITS;
            in = W2; out = W2t; K = 1536; N = 768; Npad = 768;
            bx = tb % (1536 / 64); by = tb / (1536 / 64);
        } else {
            tb -= T1_UNITS + T2_UNITS;
            in = W3; out = W3t; K = 768; N = 121; Npad = 128;
            bx = tb % (768 / 64); by = tb / (768 / 64);
        }
        int k0 = bx * 64, n0 = by * 64;

        int kr = tid >> 2;
        int nq = (tid & 3) * 16;
        if (n0 + 64 <= N) {
            #pragma unroll
            for (int j = 0; j < 4; ++j) {
                float4 vv = *(const float4*)&in[(size_t)(k0 + kr) * N + n0 + nq + j * 4];
                *(float4*)&sm.t64[kr][nq + j * 4] = vv;
            }
        } else {
            #pragma unroll
            for (int j = 0; j < 16; ++j) {
                int n = n0 + nq + j;
                sm.t64[kr][nq + j] = (n < N) ? in[(size_t)(k0 + kr) * N + n] : 0.f;
            }
        }
        __syncthreads();

        int nr = tid >> 2;
        int kq = (tid & 3) * 16;
        if (n0 + nr < Npad) {
            ushort tmp[16];
            #pragma unroll
            for (int j = 0; j < 16; ++j) tmp[j] = f2bf(sm.t64[kq + j][nr]);
            ushort* dst = out + (size_t)(n0 + nr) * K + k0 + kq;
            *(bf16x8*)dst       = *(bf16x8*)&tmp[0];
            *(bf16x8*)(dst + 8) = *(bf16x8*)&tmp[8];
        }
    }
}

// ---------------------------------------------------------------------------
// Single-wave MFMA GEMM: one 64-thread wave per block, wave owns a 64x64
// output tile (4x4 frags of 16x16x32 -> 64 acc VGPRs, 32 FLOP/LDS-byte).
// global_load_lds DMA staging, 3 buffers (48 KB -> 3 blocks/CU), counted
// vmcnt, NO barriers (single wave). lgkmcnt(0) guards buffer overwrite.
// ---------------------------------------------------------------------------
template<int WRITE_BF16, int RELU>
__global__ __launch_bounds__(64) void gemm_sw(
    const ushort* __restrict__ A,    // [M,K] bf16
    const ushort* __restrict__ Bt,   // [Npad,K] bf16
    const float* __restrict__ bias,  // [N]
    void* __restrict__ Cout,         // [M,N]
    int M, int N, int K)
{
    __shared__ ushort lds[3][128 * 64];   // [buf][(Arow 0..63 | Brow 64..127)*64+k]
    int lane = threadIdx.x;
    int row0 = blockIdx.y * 64;
    int col0 = blockIdx.x * 64;
    int rl = lane & 15;

    int srow  = lane >> 3;                     // 0..7: row within 8-row group
    int scolb = (((lane & 7) ^ srow) << 4);    // inverse-swizzled src byte col
    const char* Abase = (const char*)(A  + (size_t)row0 * K);
    const char* Bbase = (const char*)(Bt + (size_t)col0 * K);
    size_t rstride = (size_t)K * 2;

    f32x4 acc[4][4] = {};
    int nt = K >> 6;

    auto stage = [&](int buf, int t) {
        size_t kb0 = (size_t)t << 7;           // t*64 bf16 = t*128 bytes
        #pragma unroll
        for (int i = 0; i < 8; ++i) {
            int r = i * 8 + srow;
            gload16(Abase + (size_t)r * rstride + kb0 + scolb,
                    &lds[buf][(i * 8) * 64]);
            gload16(Bbase + (size_t)r * rstride + kb0 + scolb,
                    &lds[buf][(64 + i * 8) * 64]);
        }
    };

    stage(0, 0);
    stage(1, 1);

    for (int t = 0; t < nt; ++t) {
        int cur = t % 3;
        // issue stage t+2 first so its latency overlaps this step's compute
        if (t + 2 < nt) stage((t + 2) % 3, t + 2);
        // wait for stage t's 16 loads (oldest) to have landed in LDS
        if (t + 2 < nt)      asm volatile("s_waitcnt vmcnt(32)" ::: "memory");
        else if (t + 1 < nt) asm volatile("s_waitcnt vmcnt(16)" ::: "memory");
        else                 asm volatile("s_waitcnt vmcnt(0)"  ::: "memory");
        __builtin_amdgcn_sched_barrier(0);

        const char* lb = (const char*)&lds[cur][0];
        int kq = (lane >> 4) << 4;
        #pragma unroll
        for (int kk = 0; kk < 2; ++kk) {
            bf16x8 af[4], bfr[4];
            #pragma unroll
            for (int f = 0; f < 4; ++f) {
                int ar = f * 16 + rl;
                af[f]  = *(const bf16x8*)(lb + ar * 128 +
                                          ((kq + kk * 64) ^ ((ar & 7) << 4)));
                int br = 64 + f * 16 + rl;
                bfr[f] = *(const bf16x8*)(lb + br * 128 +
                                          ((kq + kk * 64) ^ ((br & 7) << 4)));
            }
            #pragma unroll
            for (int m = 0; m < 4; ++m)
                #pragma unroll
                for (int n = 0; n < 4; ++n)
                    acc[m][n] = __builtin_amdgcn_mfma_f32_16x16x32_bf16(
                        af[m], bfr[n], acc[m][n], 0, 0, 0);
        }
        // all ds_reads of buf[cur] drained before DMA may overwrite it (t+3)
        asm volatile("s_waitcnt lgkmcnt(0)" ::: "memory");
        __builtin_amdgcn_sched_barrier(0);
    }

    // epilogue: C/D layout col = lane&15, row = (lane>>4)*4 + j
    #pragma unroll
    for (int m = 0; m < 4; ++m) {
        #pragma unroll
        for (int n = 0; n < 4; ++n) {
            #pragma unroll
            for (int j = 0; j < 4; ++j) {
                int row = row0 + m * 16 + (lane >> 4) * 4 + j;
                int col = col0 + n * 16 + rl;
                if (col < N && row < M) {
                    float v = acc[m][n][j] + bias[col];
                    if (RELU) v = fmaxf(v, 0.f);
                    if (WRITE_BF16)
                        ((ushort*)Cout)[(size_t)row * N + col] = f2bf(v);
                    else
                        ((float*)Cout)[(size_t)row * N + col] = v;
                }
            }
        }
    }
}

// ---------------------------------------------------------------------------
extern "C" void kernel_launch(void* const* d_in, const int* in_sizes, int n_in,
                              void* d_out, int out_size, void* d_ws, size_t ws_size,
                              hipStream_t stream) {
    const float* emb        = (const float*)d_in[0];
    const float* W1         = (const float*)d_in[1];  // [2304,1536]
    const float* b1         = (const float*)d_in[2];
    const float* W2         = (const float*)d_in[3];  // [1536,768]
    const float* b2         = (const float*)d_in[4];
    const float* W3         = (const float*)d_in[5];  // [768,121]
    const float* b3         = (const float*)d_in[6];
    const int* span_masks   = (const int*)d_in[7];
    const int* batch_idx    = (const int*)d_in[8];
    const int* aspect_idx   = (const int*)d_in[9];
    const int* opinion_idx  = (const int*)d_in[10];
    float* out = (float*)d_out;                       // [1024,121]

    // workspace (ushort units); H2 aliases Xb (Xb dead after GEMM1)
    ushort* Xb  = (ushort*)d_ws;                        // 2,359,296
    ushort* H2  = Xb;
    ushort* W1t = Xb  + (size_t)1024 * 2304;            // 3,538,944
    ushort* W2t = W1t + (size_t)1536 * 2304;            // 1,179,648
    ushort* W3t = W2t + (size_t)768 * 1536;             // 98,304
    ushort* H1  = W3t + (size_t)128 * 768;              // 1,572,864

    fused_prep_kernel<<<PB_UNITS + T1_UNITS + T2_UNITS + T3_UNITS, 256, 0, stream>>>(
        emb, span_masks, batch_idx, aspect_idx, opinion_idx, Xb,
        W1, W1t, W2, W2t, W3, W3t);

    gemm_sw<1,1><<<dim3(1536/64, 1024/64), 64, 0, stream>>>(Xb, W1t, b1, H1, 1024, 1536, 2304);
    gemm_sw<1,1><<<dim3( 768/64, 1024/64), 64, 0, stream>>>(H1, W2t, b2, H2, 1024, 768, 1536);
    gemm_sw<0,0><<<dim3( 128/64, 1024/64), 64, 0, stream>>>(H2, W3t, b3, out, 1024, 121, 768);
}

// Round 10
// 55.334 us; speedup vs baseline: 1.8832x; 1.6310x over previous
//
#include <hip/hip_runtime.h>
#include <hip/hip_bf16.h>
#include <math.h>

#define S_LEN 128
#define D_DIM 768
#define P_PAIRS 1024
#define B_BATCH 16

typedef __attribute__((ext_vector_type(8))) short bf16x8;
typedef __attribute__((ext_vector_type(4))) float f32x4;

#define PB_UNITS (B_BATCH * (D_DIM / 64))           // 192
#define T1_UNITS ((2304 / 64) * (1536 / 64))        // 36*24 = 864
#define T2_UNITS ((1536 / 64) * (768 / 64))         // 24*12 = 288
#define T3_UNITS ((768 / 64) * (128 / 64))          // 12*2  = 24

union SmemU {
    struct {
        ushort semb[128][64];    // emb chunk, bf16-rounded
        ushort spref[128][64];   // prefix max (bf16)
        ushort ssuf[128][64];    // suffix max (bf16)
        ushort smean[64];
        float  lred[3][4][64];
        int    li;
    } pb;                        // ~52.4 KB -> 3 blocks/CU
    float t64[64][65];           // transpose tile (16.6 KB)
};

__device__ __forceinline__ ushort f2bf(float f) {
    __hip_bfloat16 h = __float2bfloat16(f);
    return *(ushort*)&h;
}

__device__ __forceinline__ float bf2f(ushort u) {
    unsigned int x = ((unsigned int)u) << 16;
    float f;
    __builtin_memcpy(&f, &x, 4);
    return f;
}

__device__ __forceinline__ void gload16(const void* g, void* l) {
    __builtin_amdgcn_global_load_lds(
        (const __attribute__((address_space(1))) void*)g,
        (__attribute__((address_space(3))) void*)l, 16, 0, 0);
}

// ---------------------------------------------------------------------------
// Fused prep kernel (unchanged from round 7).
//   blocks [0,192):     per-(batch, 64-col-chunk) span scan + X build
//   blocks [192,1368):  weight transposes, 64x64 tiles (f32 [K,N] -> bf16 [N,K])
// ---------------------------------------------------------------------------
__global__ __launch_bounds__(256) void fused_prep_kernel(
    const float* __restrict__ emb_all,   // [B,S,D]
    const int* __restrict__ span_masks,  // [B,S]
    const int* __restrict__ batch_idx,   // [P]
    const int* __restrict__ aspect_idx,  // [P]
    const int* __restrict__ opinion_idx, // [P]
    ushort* __restrict__ X,              // [P, 3*D] bf16
    const float* __restrict__ W1, ushort* __restrict__ W1t,
    const float* __restrict__ W2, ushort* __restrict__ W2t,
    const float* __restrict__ W3, ushort* __restrict__ W3t)
{
    __shared__ SmemU sm;
    int bid = blockIdx.x;
    int tid = threadIdx.x;

    if (bid < PB_UNITS) {
        // ================= span scan + X build =================
        int b = bid / (D_DIM / 64);
        int chunk = bid % (D_DIM / 64);
        int lane = tid & 63;
        int g = tid >> 6;           // wave/row-group 0..3
        int r0 = g * 32;
        int col = chunk * 64 + lane;

        if (tid == 0) {
            int s = 0;
            for (int i = 0; i < S_LEN; ++i) s += span_masks[b * S_LEN + i];
            sm.pb.li = s - 1;
        }
        __syncthreads();
        int li = sm.pb.li;

        const float* embb = emb_all + (size_t)b * S_LEN * D_DIM;

        float v[32];
        #pragma unroll
        for (int r = 0; r < 32; ++r) {
            v[r] = embb[(size_t)(r0 + r) * D_DIM + col];
            sm.pb.semb[r0 + r][lane] = f2bf(v[r]);
        }

        float wmax = -INFINITY, umax = -INFINITY, s = 0.f;
        #pragma unroll
        for (int r = 0; r < 32; ++r) {
            int gr = r0 + r;
            wmax = fmaxf(wmax, (gr == 0) ? -INFINITY : v[r]);
            bool in = (gr >= 1) && (gr < li);
            umax = fmaxf(umax, in ? v[r] : -INFINITY);
            s += in ? v[r] : 0.f;
        }
        sm.pb.lred[0][g][lane] = wmax;
        sm.pb.lred[1][g][lane] = umax;
        sm.pb.lred[2][g][lane] = s;
        __syncthreads();

        float basep = -INFINITY;
        #pragma unroll
        for (int gg = 0; gg < 3; ++gg)
            if (gg < g) basep = fmaxf(basep, sm.pb.lred[0][gg][lane]);
        float bases = -INFINITY;
        #pragma unroll
        for (int gg = 1; gg < 4; ++gg)
            if (gg > g) bases = fmaxf(bases, sm.pb.lred[1][gg][lane]);

        if (g == 0) {
            float tot = sm.pb.lred[2][0][lane] + sm.pb.lred[2][1][lane]
                      + sm.pb.lred[2][2][lane] + sm.pb.lred[2][3][lane];
            int cnt = (li - 1) > 0 ? (li - 1) : 1;
            sm.pb.smean[lane] = f2bf(tot / (float)cnt);
        }

        float m = basep;
        #pragma unroll
        for (int r = 0; r < 32; ++r) {
            int gr = r0 + r;
            m = fmaxf(m, (gr == 0) ? -INFINITY : v[r]);
            sm.pb.spref[gr][lane] = f2bf(m);
        }
        float m2 = bases;
        #pragma unroll
        for (int r = 31; r >= 0; --r) {
            int gr = r0 + r;
            bool in = (gr >= 1) && (gr < li);
            m2 = fmaxf(m2, in ? v[r] : -INFINITY);
            if (gr >= 1) sm.pb.ssuf[gr][lane] = f2bf(m2);
        }
        __syncthreads();

        // pair loop: wave g scans pairs [g*256, (g+1)*256), ballot over batch
        int pbase = g * 256;
        for (int c = 0; c < 256; c += 64) {
            int p = pbase + c + lane;
            int vb = batch_idx[p];
            int va = aspect_idx[p];
            int vo = opinion_idx[p];
            unsigned long long mask = __ballot(vb == b);
            while (mask) {
                int i = __ffsll((long long)mask) - 1;
                mask &= mask - 1;
                int pp = pbase + c + i;
                int a = __shfl(va, i);
                int o = __shfl(vo, i);
                bool both0 = (a == 0) && (o == 0);
                int bnd = (a != 0) ? a : o;
                int oe = (o == 0) ? li : o;
                float ar  = bf2f(sm.pb.semb[a][lane]);
                float orp = bf2f(sm.pb.semb[oe][lane]);
                ushort left, right;
                if (both0) {
                    left  = sm.pb.smean[lane];
                    right = sm.pb.spref[li - 1][lane];
                } else {
                    left  = (bnd == 1)  ? sm.pb.semb[0][lane]
                                        : sm.pb.spref[bnd - 1][lane];
                    right = (bnd == li) ? sm.pb.semb[li][lane]
                                        : sm.pb.ssuf[bnd][lane];
                }
                size_t base = (size_t)pp * (3 * D_DIM) + col;
                X[base]             = f2bf(ar + orp);
                X[base + D_DIM]     = left;
                X[base + 2 * D_DIM] = right;
            }
        }
    } else {
        // ================= weight transposes (64x64 tiles) =================
        int tb = bid - PB_UNITS;
        const float* in; ushort* out; int K, N, Npad, bx, by;
        if (tb < T1_UNITS) {
            in = W1; out = W1t; K = 2304; N = 1536; Npad = 1536;
            bx = tb % (2304 / 64); by = tb / (2304 / 64);
        } else if (tb < T1_UNITS + T2_UNITS) {
            tb -= T1_UNITS;
            in = W2; out = W2t; K = 1536; N = 768; Npad = 768;
            bx = tb % (1536 / 64); by = tb / (1536 / 64);
        } else {
            tb -= T1_UNITS + T2_UNITS;
            in = W3; out = W3t; K = 768; N = 121; Npad = 128;
            bx = tb % (768 / 64); by = tb / (768 / 64);
        }
        int k0 = bx * 64, n0 = by * 64;

        int kr = tid >> 2;
        int nq = (tid & 3) * 16;
        if (n0 + 64 <= N) {
            #pragma unroll
            for (int j = 0; j < 4; ++j) {
                float4 vv = *(const float4*)&in[(size_t)(k0 + kr) * N + n0 + nq + j * 4];
                *(float4*)&sm.t64[kr][nq + j * 4] = vv;
            }
        } else {
            #pragma unroll
            for (int j = 0; j < 16; ++j) {
                int n = n0 + nq + j;
                sm.t64[kr][nq + j] = (n < N) ? in[(size_t)(k0 + kr) * N + n] : 0.f;
            }
        }
        __syncthreads();

        int nr = tid >> 2;
        int kq = (tid & 3) * 16;
        if (n0 + nr < Npad) {
            ushort tmp[16];
            #pragma unroll
            for (int j = 0; j < 16; ++j) tmp[j] = f2bf(sm.t64[kq + j][nr]);
            ushort* dst = out + (size_t)(n0 + nr) * K + k0 + kq;
            *(bf16x8*)dst       = *(bf16x8*)&tmp[0];
            *(bf16x8*)(dst + 8) = *(bf16x8*)&tmp[8];
        }
    }
}

// ---------------------------------------------------------------------------
// MFMA bf16 GEMM: C[M,N] = act(A[M,K] @ Bt[N,K]^T + bias)
// 64x64 tile, BK=64, 4 waves (2x2), 3-buffer depth-2 counted-vmcnt pipeline.
// LDS 48 KB + launch_bounds(256,3) -> 3 blocks/CU (12 waves/CU).
// Bijective XCD swizzle (grid % 8 == 0 for all layers).
// ---------------------------------------------------------------------------
template<int WRITE_BF16, int RELU>
__global__ __launch_bounds__(256, 3) void gemm_mfma(
    const ushort* __restrict__ A,    // [M,K] bf16
    const ushort* __restrict__ Bt,   // [Npad,K] bf16
    const float* __restrict__ bias,  // [N]
    void* __restrict__ Cout,         // [M,N]
    int M, int N, int K)
{
    __shared__ ushort lds[3][128 * 64];
    int tid = threadIdx.x;
    int lane = tid & 63;
    int w = tid >> 6;
    int wr = w >> 1, wc = w & 1;

    // bijective XCD swizzle: contiguous work chunk per XCD (n % 8 == 0)
    int gx = gridDim.x;
    int id = blockIdx.y * gx + blockIdx.x;
    int n8 = (gx * gridDim.y) >> 3;
    int swz = (id & 7) * n8 + (id >> 3);
    int bx = swz % gx;
    int by = swz / gx;

    int rowBase = by * 64;
    int colBase = bx * 64;

    int srow  = lane >> 3;
    int scolb = (((lane & 7) ^ srow) << 4);
    const char* Abase = (const char*)(A  + (size_t)rowBase * K);
    const char* Bbase = (const char*)(Bt + (size_t)colBase * K);
    size_t rstride = (size_t)K * 2;

    f32x4 acc[2][2] = {};
    int nt = K >> 6;

    auto stage = [&](int buf, int t) {
        size_t kb0 = (size_t)t << 7;
        #pragma unroll
        for (int i = 0; i < 2; ++i) {
            int r = w * 16 + i * 8 + srow;
            gload16(Abase + (size_t)r * rstride + kb0 + scolb,
                    &lds[buf][(w * 16 + i * 8) * 64]);
        }
        #pragma unroll
        for (int i = 0; i < 2; ++i) {
            int r = w * 16 + i * 8 + srow;
            gload16(Bbase + (size_t)r * rstride + kb0 + scolb,
                    &lds[buf][(64 + w * 16 + i * 8) * 64]);
        }
    };

    stage(0, 0);
    stage(1, 1);

    int cur = 0;
    for (int t = 0; t < nt; ++t) {
        // wait for this wave's stage-t loads (4), leaving stage t+1 in flight
        if (t + 1 < nt) asm volatile("s_waitcnt vmcnt(4)" ::: "memory");
        else            asm volatile("s_waitcnt vmcnt(0)" ::: "memory");
        __builtin_amdgcn_s_barrier();   // all waves' stage-t loads landed
        __builtin_amdgcn_sched_barrier(0);

        // prefetch stage t+2 into buf[(t+2)%3] (readers of it finished at t-1)
        if (t + 2 < nt) stage((t + 2) % 3, t + 2);

        const char* lb = (const char*)&lds[cur][0];
        int kq = (lane >> 4) << 4;
        bf16x8 af[2][2], bfr[2][2];
        #pragma unroll
        for (int m = 0; m < 2; ++m) {
            int row = wr * 32 + m * 16 + (lane & 15);
            #pragma unroll
            for (int kk = 0; kk < 2; ++kk) {
                int addr = row * 128 + ((kq + kk * 64) ^ ((row & 7) << 4));
                af[m][kk] = *(const bf16x8*)(lb + addr);
            }
        }
        #pragma unroll
        for (int n = 0; n < 2; ++n) {
            int row = 64 + wc * 32 + n * 16 + (lane & 15);
            #pragma unroll
            for (int kk = 0; kk < 2; ++kk) {
                int addr = row * 128 + ((kq + kk * 64) ^ ((row & 7) << 4));
                bfr[n][kk] = *(const bf16x8*)(lb + addr);
            }
        }
        __builtin_amdgcn_s_setprio(1);
        #pragma unroll
        for (int m = 0; m < 2; ++m)
            #pragma unroll
            for (int n = 0; n < 2; ++n)
                #pragma unroll
                for (int kk = 0; kk < 2; ++kk)
                    acc[m][n] = __builtin_amdgcn_mfma_f32_16x16x32_bf16(
                        af[m][kk], bfr[n][kk], acc[m][n], 0, 0, 0);
        __builtin_amdgcn_s_setprio(0);
        cur = (cur + 1) % 3;
    }

    #pragma unroll
    for (int m = 0; m < 2; ++m) {
        #pragma unroll
        for (int n = 0; n < 2; ++n) {
            #pragma unroll
            for (int j = 0; j < 4; ++j) {
                int row = rowBase + wr * 32 + m * 16 + (lane >> 4) * 4 + j;
                int col = colBase + wc * 32 + n * 16 + (lane & 15);
                if (col < N && row < M) {
                    float v = acc[m][n][j] + bias[col];
                    if (RELU) v = fmaxf(v, 0.f);
                    if (WRITE_BF16)
                        ((ushort*)Cout)[(size_t)row * N + col] = f2bf(v);
                    else
                        ((float*)Cout)[(size_t)row * N + col] = v;
                }
            }
        }
    }
}

// ---------------------------------------------------------------------------
extern "C" void kernel_launch(void* const* d_in, const int* in_sizes, int n_in,
                              void* d_out, int out_size, void* d_ws, size_t ws_size,
                              hipStream_t stream) {
    const float* emb        = (const float*)d_in[0];
    const float* W1         = (const float*)d_in[1];  // [2304,1536]
    const float* b1         = (const float*)d_in[2];
    const float* W2         = (const float*)d_in[3];  // [1536,768]
    const float* b2         = (const float*)d_in[4];
    const float* W3         = (const float*)d_in[5];  // [768,121]
    const float* b3         = (const float*)d_in[6];
    const int* span_masks   = (const int*)d_in[7];
    const int* batch_idx    = (const int*)d_in[8];
    const int* aspect_idx   = (const int*)d_in[9];
    const int* opinion_idx  = (const int*)d_in[10];
    float* out = (float*)d_out;                       // [1024,121]

    // workspace (ushort units); H2 aliases Xb (Xb dead after GEMM1)
    ushort* Xb  = (ushort*)d_ws;                        // 2,359,296
    ushort* H2  = Xb;
    ushort* W1t = Xb  + (size_t)1024 * 2304;            // 3,538,944
    ushort* W2t = W1t + (size_t)1536 * 2304;            // 1,179,648
    ushort* W3t = W2t + (size_t)768 * 1536;             // 98,304
    ushort* H1  = W3t + (size_t)128 * 768;              // 1,572,864

    fused_prep_kernel<<<PB_UNITS + T1_UNITS + T2_UNITS + T3_UNITS, 256, 0, stream>>>(
        emb, span_masks, batch_idx, aspect_idx, opinion_idx, Xb,
        W1, W1t, W2, W2t, W3, W3t);

    gemm_mfma<1,1><<<dim3(1536/64, 1024/64), 256, 0, stream>>>(Xb, W1t, b1, H1, 1024, 1536, 2304);
    gemm_mfma<1,1><<<dim3( 768/64, 1024/64), 256, 0, stream>>>(H1, W2t, b2, H2, 1024, 768, 1536);
    gemm_mfma<0,0><<<dim3( 128/64, 1024/64), 256, 0, stream>>>(H2, W3t, b3, out, 1024, 121, 768);
}